// Round 4
// baseline (523.094 us; speedup 1.0000x reference)
//
#include <hip/hip_runtime.h>
#include <math.h>

#define S 128
#define L (S*S)            // 16384
#define AK 25
#define KA 625
#define LK 49
#define KL 2401
#define KJ 2552            // permuted lateral row: 49 rows x 52 cols + pad to x8 (gaps = 0)
#define XW 152
#define PI2 1.57079632679489662f
#define MSCALE 1024.0f

typedef float v4f __attribute__((ext_vector_type(4)));
typedef _Float16 v8h __attribute__((ext_vector_type(8)));

// ws layout (float offsets)
#define WS_AENVD   0        // deinterleaved aff env, 628 floats
#define WS_SRE     640      // 25 floats
#define WS_LRID    672      // deinterleaved lri env, 2404 floats
#define WS_LRIRAW  4096     // scratch 2401
#define WS_AFF     8192
#define WS_LATA    40960
#define WS_LATB    57344
#define WS_LM      73728
#define WS_M16     102400   // fp16 premultiplied weights, window-order layout, 16384*2552 halves

// out layout (float offsets): raw_aff[16384], lat[16384], corr[1], x_tiles[10240000]
#define OUT_LAT   16384
#define OUT_CORR  32768
#define OUT_XT    32769

__global__ __launch_bounds__(256) void init_consts(float* __restrict__ ws) {
    const int t = threadIdx.x;
    float* aenvd  = ws + WS_AENVD;
    float* sre    = ws + WS_SRE;
    float* lrraw  = ws + WS_LRIRAW;
    float* lrid   = ws + WS_LRID;
    __shared__ float red[256];

    for (int k = t; k < KA; k += 256) {
        int ky = k / AK, kx = k - ky * AK;
        float dy = (float)ky - 12.0f, dx = (float)kx - 12.0f;
        float rd = sqrtf(dx*dx + dy*dy);
        float c  = cosf(fminf(rd * (1.0f/25.0f), 1.0f) * PI2);
        aenvd[(k & 3) * 157 + (k >> 2)] = c*c * (rd < 12.5f ? 1.0f : 0.0f);
    }

    float myv = 0.0f;
    if (t < 25) {
        int ky = t / 5, kx = t - ky * 5;
        float dy = (float)ky - 2.0f, dx = (float)kx - 2.0f;
        float rd = sqrtf(dx*dx + dy*dy);
        float c  = cosf(fminf(rd * 0.2f, 1.0f) * PI2);
        myv = c*c * (rd < 2.5f ? 1.0f : 0.0f);
    }
    red[t] = myv;
    __syncthreads();
    for (int off = 128; off > 0; off >>= 1) {
        if (t < off) red[t] += red[t + off];
        __syncthreads();
    }
    float ssum = red[0];
    __syncthreads();
    if (t < 25) sre[t] = myv / ssum;

    float localmax = 0.0f;
    for (int k = t; k < KL; k += 256) {
        int ky = k / LK, kx = k - ky * LK;
        float dy = (float)ky - 24.0f, dx = (float)kx - 24.0f;
        float rd = sqrtf(dx*dx + dy*dy);
        float ci = cosf(fminf(rd * 0.2f, 1.0f) * PI2);
        float im = ci*ci * (rd < 2.5f ? 1.0f : 0.0f);
        float co = cosf(fminf(rd * (1.0f/49.0f), 1.0f) * PI2);
        float le = co*co * (rd < 24.5f ? 1.0f : 0.0f) * (1.0f - im);
        lrraw[k] = le;
        localmax = fmaxf(localmax, le);
    }
    red[t] = localmax;
    __syncthreads();
    for (int off = 128; off > 0; off >>= 1) {
        if (t < off) red[t] = fmaxf(red[t], red[t + off]);
        __syncthreads();
    }
    float invm = 1.0f / red[0];
    __syncthreads();
    for (int k = t; k < KL; k += 256)
        lrid[(k & 3) * 601 + (k >> 2)] = lrraw[k] * invm;
}

// Precompute M16 in "window order": row length KJ=2552, position j = k + 3*(k/49),
// gap slots (kx>=49 and tail pad) are ZERO. m16[l,j] = fp16( lw[l,k]*lri[k]*MSCALE/wsum[l] ).
// Staged v4f bulk loads (latency cover) -> premult+scatter to per-wave LDS in j-order ->
// linear j-order readback + coalesced v8h stores.
__global__ __launch_bounds__(256) void prep_kernel(
    const float* __restrict__ lw, const float* __restrict__ lri_d,
    _Float16* __restrict__ m16)
{
    __shared__ float lriS[2404];
    __shared__ float jbuf[4][2560];   // per-wave, deinterleaved: (j&3)*640 + (j>>2)
    const int tid = threadIdx.x;
    const int wave = tid >> 6, lane = tid & 63;
    for (int i = tid; i < 2404; i += 256) lriS[i] = lri_d[i];

    const int unit = blockIdx.x * 4 + wave;
    const int base = unit * KL;
    const int h = (-base) & 3;
    const int tl = (base + KL) & 3;
    const int m4 = (KL - h - tl) >> 2;
    const int rem = m4 - 576;

    // issue all global loads up front (~9.2 KB in flight per wave)
    const v4f* w4p = (const v4f*)(lw + base + h);
    v4f wv[9];
    #pragma unroll
    for (int i = 0; i < 9; i++) wv[i] = w4p[lane + (i << 6)];
    v4f wv9 = (v4f)(0.0f);
    bool has9 = lane < rem;
    if (has9) wv9 = w4p[576 + lane];
    float whd = 0.0f, wtl = 0.0f;
    if (lane < h)  whd = lw[base + lane];
    if (lane < tl) wtl = lw[base + KL - tl + lane];

    // zero gap slots of own jbuf: j = 52*ky + 49+g (147 slots) and 2548..2551
    float* jb = jbuf[wave];
    for (int id = lane; id < 147; id += 64) {
        int ky = (id * 21846) >> 16;      // id/3 for id < 147
        int g  = id - 3 * ky;
        int j  = 52 * ky + 49 + g;
        jb[(j & 3) * 640 + (j >> 2)] = 0.0f;
    }
    if (lane < 4) { int j = 2548 + lane; jb[(j & 3) * 640 + (j >> 2)] = 0.0f; }

    float wsum = whd + wtl;
    #pragma unroll
    for (int i = 0; i < 9; i++) wsum += wv[i][0] + wv[i][1] + wv[i][2] + wv[i][3];
    wsum += wv9[0] + wv9[1] + wv9[2] + wv9[3];
    #pragma unroll
    for (int off = 1; off < 64; off <<= 1) wsum += __shfl_xor(wsum, off);
    const float scale = MSCALE / wsum;

    __syncthreads();   // lriS ready

    // phase A: premultiply by lri, scatter into j-order LDS (stride-1 per instr -> conflict-free)
    if (lane < h) {
        int k = lane;                      // ky = 0 -> j = k
        jb[(k & 3) * 640 + (k >> 2)] = whd * lriS[(k & 3) * 601 + (k >> 2)];
    }
    if (lane < tl) {
        int k = KL - tl + lane;
        int ky = (int)(((unsigned)k * 42800u) >> 21);
        int j = k + 3 * ky;
        jb[(j & 3) * 640 + (j >> 2)] = wtl * lriS[(k & 3) * 601 + (k >> 2)];
    }
    #pragma unroll
    for (int i = 0; i < 9; i++) {
        int kq = h + ((lane + (i << 6)) << 2);
        #pragma unroll
        for (int e = 0; e < 4; e++) {
            int k = kq + e;
            int ky = (int)(((unsigned)k * 42800u) >> 21);
            int j = k + 3 * ky;
            jb[(j & 3) * 640 + (j >> 2)] = wv[i][e] * lriS[(k & 3) * 601 + (k >> 2)];
        }
    }
    if (has9) {
        int kq = h + ((576 + lane) << 2);
        #pragma unroll
        for (int e = 0; e < 4; e++) {
            int k = kq + e;
            int ky = (int)(((unsigned)k * 42800u) >> 21);
            int j = k + 3 * ky;
            jb[(j & 3) * 640 + (j >> 2)] = wv9[e] * lriS[(k & 3) * 601 + (k >> 2)];
        }
    }

    // phase B: linear j-order readback (2-way = free), scale, cvt, coalesced v8h store
    v8h* orow = (v8h*)(m16 + (size_t)unit * KJ);
    #pragma unroll
    for (int g = 0; g < 5; g++) {
        int q = lane + (g << 6);
        if (q < 319) {
            int j0 = q << 3;
            v8h st;
            #pragma unroll
            for (int e = 0; e < 8; e++) {
                int j = j0 + e;
                st[e] = (_Float16)(jb[(j & 3) * 640 + (j >> 2)] * scale);
            }
            orow[q] = st;
        }
    }
}

// Afferent: unchanged structure; additionally zeroes the corr accumulator.
__global__ __launch_bounds__(256) void aff_kernel(
    const float* __restrict__ x, const float* __restrict__ rfs,
    const float* __restrict__ ada, const float* __restrict__ aenv_d,
    float* __restrict__ raw_aff_out, float* __restrict__ xtiles_out,
    float* __restrict__ aff_ws, float* __restrict__ corr)
{
    __shared__ float xwin[700];
    __shared__ float env[628];
    const int tid = threadIdx.x;
    const int wave = tid >> 6, lane = tid & 63;
    const int unit0 = blockIdx.x * 4;
    const int r0 = unit0 >> 7, c0 = unit0 & 127;

    if (blockIdx.x == 0 && tid == 0) corr[0] = 0.0f;

    for (int i = tid; i < 628; i += 256) env[i] = aenv_d[i];
    for (int i = tid; i < 700; i += 256) {
        int wy = i / 28, wx = i - wy * 28;
        xwin[(i & 3) * 175 + (i >> 2)] = x[(r0 + wy) * XW + c0 + wx];
    }
    __syncthreads();

    const int unit = unit0 + wave;
    const int base = unit * KA;
    const int h = (-base) & 3;
    const int tl = (base + KA) & 3;
    const int m4 = (KA - h - tl) >> 2;
    const int rem = m4 - 128;

    const v4f* w4p = (const v4f*)(rfs + base + h);
    v4f wv0 = w4p[lane];
    v4f wv1 = w4p[lane + 64];
    v4f wv2 = (v4f)(0.0f);
    bool has2 = lane < rem;
    if (has2) wv2 = w4p[128 + lane];
    float wh = 0.0f, wt = 0.0f;
    if (lane < h)  wh = rfs[base + lane];
    if (lane < tl) wt = rfs[base + KA - tl + lane];

    float* trow = xtiles_out + (size_t)unit * KA;
    v4f* t4p = (v4f*)(trow + h);
    float adot = 0.0f, rsum = 0.0f;

    if (lane < h) {
        int j = lane + wave;
        float xt = xwin[(j & 3) * 175 + (j >> 2)] * env[(lane & 3) * 157 + (lane >> 2)];
        trow[lane] = xt;
        adot = fmaf(xt, wh, adot); rsum += wh;
    }
    if (lane < tl) {
        int k = KA - tl + lane;
        int ky = (int)(((unsigned)k * 83887u) >> 21);
        int j = k + 3 * ky + wave;
        float xt = xwin[(j & 3) * 175 + (j >> 2)] * env[(k & 3) * 157 + (k >> 2)];
        trow[k] = xt;
        adot = fmaf(xt, wt, adot); rsum += wt;
    }
    #pragma unroll
    for (int i = 0; i < 2; i++) {
        v4f wq = (i == 0) ? wv0 : wv1;
        int q = lane + (i << 6);
        int kq = h + (q << 2);
        v4f st;
        #pragma unroll
        for (int e = 0; e < 4; e++) {
            int k = kq + e;
            int ky = (int)(((unsigned)k * 83887u) >> 21);
            int j = k + 3 * ky + wave;
            float xt = xwin[(j & 3) * 175 + (j >> 2)] * env[(k & 3) * 157 + (k >> 2)];
            st[e] = xt;
            adot = fmaf(xt, wq[e], adot);
            rsum += wq[e];
        }
        __builtin_nontemporal_store(st, &t4p[q]);
    }
    if (has2) {
        int q = 128 + lane;
        int kq = h + (q << 2);
        v4f st;
        #pragma unroll
        for (int e = 0; e < 4; e++) {
            int k = kq + e;
            int ky = (int)(((unsigned)k * 83887u) >> 21);
            int j = k + 3 * ky + wave;
            float xt = xwin[(j & 3) * 175 + (j >> 2)] * env[(k & 3) * 157 + (k >> 2)];
            st[e] = xt;
            adot = fmaf(xt, wv2[e], adot);
            rsum += wv2[e];
        }
        __builtin_nontemporal_store(st, &t4p[q]);
    }

    for (int off = 32; off > 0; off >>= 1) {
        adot += __shfl_down(adot, off);
        rsum += __shfl_down(rsum, off);
    }
    if (lane == 0) {
        float inv = 1.0f / rsum;
        raw_aff_out[unit] = 62.5f * adot * inv;
        aff_ws[unit] = adot * inv - ada[unit];
    }
}

// weight loads for one unit row (KJ = 2552 halves = 319 v8h groups)
#define LOADW(P, W0, W1, W2, W3, W4) \
    v8h W0 = (P)[lane]; v8h W1 = (P)[lane + 64]; v8h W2 = (P)[lane + 128]; \
    v8h W3 = (P)[lane + 192]; v8h W4 = (v8h)(_Float16)0.0f; \
    if (lane < 63) W4 = (P)[256 + lane];

// window-order dot. Element (row r, elem e) reads widx = 8*lane + 512*r + (woff+e).
// Pair (e, e+4): same (&3) class, dword addresses adjacent -> ds_read2_b32 merge.
__device__ __forceinline__ float dot_row(v8h w0, v8h w1, v8h w2, v8h w3, v8h w4,
                                         int lane, int woff, const float* win)
{
    float dot = 0.0f;
    const int a0 = lane << 1;
    #pragma unroll
    for (int eh = 0; eh < 4; eh++) {
        const int c = woff + eh;
        const int ae = a0 + (c & 3) * 676 + (c >> 2);
        #pragma unroll
        for (int r = 0; r < 5; r++) {
            const float lo = win[ae + r * 128];
            const float hi = win[ae + r * 128 + 1];
            const v8h w = (r == 0) ? w0 : (r == 1) ? w1 : (r == 2) ? w2
                        : (r == 3) ? w3 : w4;
            dot = fmaf((float)w[eh],     lo, dot);
            dot = fmaf((float)w[eh + 4], hi, dot);
        }
    }
    return dot;
}

__device__ __forceinline__ void lat_epi(float dot, int lane, int wave, int du,
    int unit, const float* win, const float* __restrict__ aff,
    const float* __restrict__ lm_in, float* __restrict__ lm_out,
    float* __restrict__ lat_out, float* __restrict__ lat_final)
{
    #pragma unroll
    for (int off = 32; off > 0; off >>= 1) dot += __shfl_down(dot, off);
    if (lane == 0) {
        const int ci = (24 + wave) * 52 + 24 + du;
        const float ls = win[(ci & 3) * 676 + (ci >> 2)];
        float ln = fmaxf(ls + aff[unit] - (2.5f / MSCALE) * dot, 0.0f) * 2.2f;
        ln = tanhf(ln * 1.5f) * (1.0f / 1.5f);
        lm_out[unit] = 0.5f * lm_in[unit] + 0.5f * ln;
        lat_out[unit] = ln;
        if (lat_final) lat_final[unit] = ln;
    }
}

// Fused smooth+lateral iteration. Block = 4x4 unit tile, wave w owns unit row r0+w (4 units).
// Stages raw lat (56x56, reflect), smooths 5x5 into swizzled 52x52 win (4 outputs/thread
// via ds_read_b128), then 4 window-order dots.
__global__ __launch_bounds__(256) void lat_kernel(
    const _Float16* __restrict__ m16, const float* __restrict__ lat_in,
    const float* __restrict__ sre_g, const float* __restrict__ aff,
    const float* __restrict__ lm_in, float* __restrict__ lm_out,
    float* __restrict__ lat_out, float* __restrict__ lat_final)
{
    __shared__ float raw[3136];      // 56x56 raw lat window (reflect-indexed), 16B aligned
    __shared__ float win[2708];      // swizzled smoothed window + 4 zero slots
    const int tid = threadIdx.x;
    const int wave = tid >> 6, lane = tid & 63;
    const int r0 = (blockIdx.x >> 5) << 2, c0 = (blockIdx.x & 31) << 2;

    for (int i = tid; i < 3136; i += 256) {
        int wy = i / 56, wx = i - wy * 56;
        int ar = r0 - 26 + wy; ar = ar < 0 ? -ar : (ar > 127 ? 254 - ar : ar);
        int ac = c0 - 26 + wx; ac = ac < 0 ? -ac : (ac > 127 ? 254 - ac : ac);
        raw[i] = lat_in[ar * 128 + ac];
    }
    if (tid < 4) win[2704 + tid] = 0.0f;

    float sr[25];
    #pragma unroll
    for (int j = 0; j < 25; j++) sr[j] = sre_g[j];

    const int urow = r0 + wave;
    const v8h* p8 = (const v8h*)(m16 + (size_t)(urow * 128 + c0) * KJ);
    LOADW(p8, a0w, a1w, a2w, a3w, a4w)      // du=0 prefetch overlaps smoothing

    __syncthreads();

    // smooth: 676 quads of 4 outputs; per quad-row 2x ds_read_b128 (16B aligned)
    for (int q = tid; q < 676; q += 256) {
        const int wr  = (q * 5042) >> 16;          // q/13, exact for q<677
        const int wc4 = (q - wr * 13) << 2;
        const int arr = r0 - 24 + wr;
        const int ac0 = c0 - 24 + wc4;
        const float* rp = raw + wr * 56 + wc4;
        v4f acc = (v4f)(0.0f);
        #pragma unroll
        for (int ay = 0; ay < 5; ay++) {
            const v4f wlo = *(const v4f*)(rp + ay * 56);
            const v4f whi = *(const v4f*)(rp + ay * 56 + 4);
            const float e0 = wlo[0], e1 = wlo[1], e2 = wlo[2], e3 = wlo[3];
            const float e4 = whi[0], e5 = whi[1], e6 = whi[2], e7 = whi[3];
            const float s0 = sr[ay*5+0], s1 = sr[ay*5+1], s2 = sr[ay*5+2],
                        s3 = sr[ay*5+3], s4 = sr[ay*5+4];
            acc[0] = fmaf(s0,e0,fmaf(s1,e1,fmaf(s2,e2,fmaf(s3,e3,fmaf(s4,e4,acc[0])))));
            acc[1] = fmaf(s0,e1,fmaf(s1,e2,fmaf(s2,e3,fmaf(s3,e4,fmaf(s4,e5,acc[1])))));
            acc[2] = fmaf(s0,e2,fmaf(s1,e3,fmaf(s2,e4,fmaf(s3,e5,fmaf(s4,e6,acc[2])))));
            acc[3] = fmaf(s0,e3,fmaf(s1,e4,fmaf(s2,e5,fmaf(s3,e6,fmaf(s4,e7,acc[3])))));
        }
        const bool rowok = ((unsigned)arr < 128u);
        #pragma unroll
        for (int o = 0; o < 4; o++) {
            const int i = wr * 52 + wc4 + o;
            const float v = (rowok && ((unsigned)(ac0 + o) < 128u)) ? acc[o] : 0.0f;
            win[(i & 3) * 676 + (i >> 2)] = v;
        }
    }
    __syncthreads();

    const int woff = wave * 52;
    const int ub = urow * 128 + c0;

    const v8h* q1 = (const v8h*)(m16 + (size_t)(ub + 1) * KJ);
    LOADW(q1, b0w, b1w, b2w, b3w, b4w)
    float d0 = dot_row(a0w, a1w, a2w, a3w, a4w, lane, woff + 0, win);
    const v8h* q2 = (const v8h*)(m16 + (size_t)(ub + 2) * KJ);
    LOADW(q2, c0w, c1w, c2w, c3w, c4w)
    lat_epi(d0, lane, wave, 0, ub + 0, win, aff, lm_in, lm_out, lat_out, lat_final);
    float d1 = dot_row(b0w, b1w, b2w, b3w, b4w, lane, woff + 1, win);
    const v8h* q3 = (const v8h*)(m16 + (size_t)(ub + 3) * KJ);
    LOADW(q3, e0w, e1w, e2w, e3w, e4w)
    lat_epi(d1, lane, wave, 1, ub + 1, win, aff, lm_in, lm_out, lat_out, lat_final);
    float d2 = dot_row(c0w, c1w, c2w, c3w, c4w, lane, woff + 2, win);
    lat_epi(d2, lane, wave, 2, ub + 2, win, aff, lm_in, lm_out, lat_out, lat_final);
    float d3 = dot_row(e0w, e1w, e2w, e3w, e4w, lane, woff + 3, win);
    lat_epi(d3, lane, wave, 3, ub + 3, win, aff, lm_in, lm_out, lat_out, lat_final);
}

// Hebbian: same 4x4 tiling, window of lm (zero pad), one atomicAdd per block.
__global__ __launch_bounds__(256) void hebb_kernel(
    const _Float16* __restrict__ m16, const float* __restrict__ lm,
    float* __restrict__ corr)
{
    __shared__ float win[2708];
    __shared__ float wred[4];
    const int tid = threadIdx.x;
    const int wave = tid >> 6, lane = tid & 63;
    const int r0 = (blockIdx.x >> 5) << 2, c0 = (blockIdx.x & 31) << 2;

    for (int i = tid; i < 2704; i += 256) {
        int wr = i / 52, wc = i - wr * 52;
        int ar = r0 - 24 + wr, ac = c0 - 24 + wc;
        float v = 0.0f;
        if (((unsigned)ar < 128u) && ((unsigned)ac < 128u)) v = lm[ar * 128 + ac];
        win[(i & 3) * 676 + (i >> 2)] = v;
    }
    if (tid < 4) win[2704 + tid] = 0.0f;
    __syncthreads();

    const int urow = r0 + wave;
    const int woff = wave * 52;
    float bsum = 0.0f;
    #pragma unroll
    for (int du = 0; du < 4; ++du) {
        const v8h* p = (const v8h*)(m16 + (size_t)(urow * 128 + c0 + du) * KJ);
        LOADW(p, w0, w1, w2, w3, w4)
        float d = dot_row(w0, w1, w2, w3, w4, lane, woff + du, win);
        #pragma unroll
        for (int off = 32; off > 0; off >>= 1) d += __shfl_down(d, off);
        if (lane == 0) {
            const int ci = (24 + wave) * 52 + 24 + du;
            bsum = fmaf(win[(ci & 3) * 676 + (ci >> 2)], d, bsum);
        }
    }
    if (lane == 0) wred[wave] = bsum;
    __syncthreads();
    if (tid == 0)
        atomicAdd(corr, (wred[0] + wred[1] + wred[2] + wred[3]) * (240.1f / MSCALE));
}

extern "C" void kernel_launch(void* const* d_in, const int* in_sizes, int n_in,
                              void* d_out, int out_size, void* d_ws, size_t ws_size,
                              hipStream_t stream) {
    const float* x        = (const float*)d_in[0];
    const float* rfs      = (const float*)d_in[1];
    const float* lw       = (const float*)d_in[2];
    const float* ada      = (const float*)d_in[3];
    const float* last_lat = (const float*)d_in[4];
    const float* lm0      = (const float*)d_in[5];
    float* out = (float*)d_out;
    float* ws  = (float*)d_ws;
    _Float16* m16 = (_Float16*)(ws + WS_M16);

    init_consts<<<1, 256, 0, stream>>>(ws);
    aff_kernel<<<L / 4, 256, 0, stream>>>(x, rfs, ada, ws + WS_AENVD,
                                          out, out + OUT_XT, ws + WS_AFF, out + OUT_CORR);
    prep_kernel<<<L / 4, 256, 0, stream>>>(lw, ws + WS_LRID, m16);

    float* bufA = ws + WS_LATA;
    float* bufB = ws + WS_LATB;
    for (int it = 0; it < 10; ++it) {
        const float* lat_in = (it == 0) ? last_lat : ((it & 1) ? bufA : bufB);
        float* lat_out = (it & 1) ? bufB : bufA;     // ping-pong: blocks read halo of lat_in
        const float* lmsrc = (it == 0) ? lm0 : (ws + WS_LM);
        lat_kernel<<<1024, 256, 0, stream>>>(m16, lat_in, ws + WS_SRE, ws + WS_AFF,
                                             lmsrc, ws + WS_LM, lat_out,
                                             (it == 9) ? (out + OUT_LAT) : nullptr);
    }
    hebb_kernel<<<1024, 256, 0, stream>>>(m16, ws + WS_LM, out + OUT_CORR);
}

// Round 7
// 506.888 us; speedup vs baseline: 1.0320x; 1.0320x over previous
//
#include <hip/hip_runtime.h>
#include <math.h>

#define S 128
#define L (S*S)            // 16384
#define AK 25
#define KA 625
#define LK 49
#define KL 2401
#define KJ 2552            // permuted lateral row: 49 rows x 52 cols + pad to x8 (gaps = 0)
#define XW 152
#define PI2 1.57079632679489662f
#define MSCALE 1024.0f

typedef float v4f __attribute__((ext_vector_type(4)));
typedef _Float16 v8h __attribute__((ext_vector_type(8)));

// ws layout (float offsets)
#define WS_AENVD   0
#define WS_SRE     640
#define WS_LRID    672
#define WS_LRIRAW  4096
#define WS_AFF     8192
#define WS_LATA    40960
#define WS_LATB    57344
#define WS_LM      73728
#define WS_M16     102400

// out layout (float offsets)
#define OUT_LAT   16384
#define OUT_CORR  32768
#define OUT_XT    32769

__global__ __launch_bounds__(256) void init_consts(float* __restrict__ ws) {
    const int t = threadIdx.x;
    float* aenvd  = ws + WS_AENVD;
    float* sre    = ws + WS_SRE;
    float* lrraw  = ws + WS_LRIRAW;
    float* lrid   = ws + WS_LRID;
    __shared__ float red[256];

    for (int k = t; k < KA; k += 256) {
        int ky = k / AK, kx = k - ky * AK;
        float dy = (float)ky - 12.0f, dx = (float)kx - 12.0f;
        float rd = sqrtf(dx*dx + dy*dy);
        float c  = cosf(fminf(rd * (1.0f/25.0f), 1.0f) * PI2);
        aenvd[(k & 3) * 157 + (k >> 2)] = c*c * (rd < 12.5f ? 1.0f : 0.0f);
    }

    float myv = 0.0f;
    if (t < 25) {
        int ky = t / 5, kx = t - ky * 5;
        float dy = (float)ky - 2.0f, dx = (float)kx - 2.0f;
        float rd = sqrtf(dx*dx + dy*dy);
        float c  = cosf(fminf(rd * 0.2f, 1.0f) * PI2);
        myv = c*c * (rd < 2.5f ? 1.0f : 0.0f);
    }
    red[t] = myv;
    __syncthreads();
    for (int off = 128; off > 0; off >>= 1) {
        if (t < off) red[t] += red[t + off];
        __syncthreads();
    }
    float ssum = red[0];
    __syncthreads();
    if (t < 25) sre[t] = myv / ssum;

    float localmax = 0.0f;
    for (int k = t; k < KL; k += 256) {
        int ky = k / LK, kx = k - ky * LK;
        float dy = (float)ky - 24.0f, dx = (float)kx - 24.0f;
        float rd = sqrtf(dx*dx + dy*dy);
        float ci = cosf(fminf(rd * 0.2f, 1.0f) * PI2);
        float im = ci*ci * (rd < 2.5f ? 1.0f : 0.0f);
        float co = cosf(fminf(rd * (1.0f/49.0f), 1.0f) * PI2);
        float le = co*co * (rd < 24.5f ? 1.0f : 0.0f) * (1.0f - im);
        lrraw[k] = le;
        localmax = fmaxf(localmax, le);
    }
    red[t] = localmax;
    __syncthreads();
    for (int off = 128; off > 0; off >>= 1) {
        if (t < off) red[t] = fmaxf(red[t], red[t + off]);
        __syncthreads();
    }
    float invm = 1.0f / red[0];
    __syncthreads();
    for (int k = t; k < KL; k += 256)
        lrid[(k & 3) * 601 + (k >> 2)] = lrraw[k] * invm;
}

// ---- Fused front kernel: blocks [0,4096) = afferent, [4096,8192) = m16 prep ----
// Pure block-range composition of the two round-3-proven kernels. No new sync.
__global__ __launch_bounds__(256) void front_kernel(
    const float* __restrict__ x, const float* __restrict__ rfs,
    const float* __restrict__ ada, const float* __restrict__ aenv_d,
    float* __restrict__ raw_aff_out, float* __restrict__ xtiles_out,
    float* __restrict__ aff_ws, float* __restrict__ corr,
    const float* __restrict__ lw, const float* __restrict__ lri_d,
    _Float16* __restrict__ m16)
{
    __shared__ union FrontLds {
        struct { float xwin[700]; float env[628]; } a;
        struct { float lriS[2404]; float jbuf[4][2560]; } p;
    } U;
    const int tid = threadIdx.x;
    const int wave = tid >> 6, lane = tid & 63;

    if (blockIdx.x < 4096) {
        // ---------------- afferent ----------------
        float* xwin = U.a.xwin;
        float* env  = U.a.env;
        const int unit0 = blockIdx.x * 4;
        const int r0 = unit0 >> 7, c0 = unit0 & 127;

        if (blockIdx.x == 0 && tid == 0) corr[0] = 0.0f;

        for (int i = tid; i < 628; i += 256) env[i] = aenv_d[i];
        for (int i = tid; i < 700; i += 256) {
            int wy = i / 28, wx = i - wy * 28;
            xwin[(i & 3) * 175 + (i >> 2)] = x[(r0 + wy) * XW + c0 + wx];
        }
        __syncthreads();

        const int unit = unit0 + wave;
        const int base = unit * KA;
        const int h = (-base) & 3;
        const int tl = (base + KA) & 3;
        const int m4 = (KA - h - tl) >> 2;
        const int rem = m4 - 128;

        const v4f* w4p = (const v4f*)(rfs + base + h);
        v4f wv0 = w4p[lane];
        v4f wv1 = w4p[lane + 64];
        v4f wv2 = (v4f)(0.0f);
        bool has2 = lane < rem;
        if (has2) wv2 = w4p[128 + lane];
        float wh = 0.0f, wt = 0.0f;
        if (lane < h)  wh = rfs[base + lane];
        if (lane < tl) wt = rfs[base + KA - tl + lane];

        float* trow = xtiles_out + (size_t)unit * KA;
        v4f* t4p = (v4f*)(trow + h);
        float adot = 0.0f, rsum = 0.0f;

        if (lane < h) {
            int j = lane + wave;
            float xt = xwin[(j & 3) * 175 + (j >> 2)] * env[(lane & 3) * 157 + (lane >> 2)];
            trow[lane] = xt;
            adot = fmaf(xt, wh, adot); rsum += wh;
        }
        if (lane < tl) {
            int k = KA - tl + lane;
            int ky = (int)(((unsigned)k * 83887u) >> 21);
            int j = k + 3 * ky + wave;
            float xt = xwin[(j & 3) * 175 + (j >> 2)] * env[(k & 3) * 157 + (k >> 2)];
            trow[k] = xt;
            adot = fmaf(xt, wt, adot); rsum += wt;
        }
        #pragma unroll
        for (int i = 0; i < 2; i++) {
            v4f wq = (i == 0) ? wv0 : wv1;
            int q = lane + (i << 6);
            int kq = h + (q << 2);
            v4f st;
            #pragma unroll
            for (int e = 0; e < 4; e++) {
                int k = kq + e;
                int ky = (int)(((unsigned)k * 83887u) >> 21);
                int j = k + 3 * ky + wave;
                float xt = xwin[(j & 3) * 175 + (j >> 2)] * env[(k & 3) * 157 + (k >> 2)];
                st[e] = xt;
                adot = fmaf(xt, wq[e], adot);
                rsum += wq[e];
            }
            __builtin_nontemporal_store(st, &t4p[q]);
        }
        if (has2) {
            int q = 128 + lane;
            int kq = h + (q << 2);
            v4f st;
            #pragma unroll
            for (int e = 0; e < 4; e++) {
                int k = kq + e;
                int ky = (int)(((unsigned)k * 83887u) >> 21);
                int j = k + 3 * ky + wave;
                float xt = xwin[(j & 3) * 175 + (j >> 2)] * env[(k & 3) * 157 + (k >> 2)];
                st[e] = xt;
                adot = fmaf(xt, wv2[e], adot);
                rsum += wv2[e];
            }
            __builtin_nontemporal_store(st, &t4p[q]);
        }

        for (int off = 32; off > 0; off >>= 1) {
            adot += __shfl_down(adot, off);
            rsum += __shfl_down(rsum, off);
        }
        if (lane == 0) {
            float inv = 1.0f / rsum;
            raw_aff_out[unit] = 62.5f * adot * inv;
            aff_ws[unit] = adot * inv - ada[unit];
        }
    } else {
        // ---------------- prep (window-order m16) ----------------
        float* lriS = U.p.lriS;
        for (int i = tid; i < 2404; i += 256) lriS[i] = lri_d[i];

        const int unit = (blockIdx.x - 4096) * 4 + wave;
        const int base = unit * KL;
        const int h = (-base) & 3;
        const int tl = (base + KL) & 3;
        const int m4 = (KL - h - tl) >> 2;
        const int rem = m4 - 576;

        const v4f* w4p = (const v4f*)(lw + base + h);
        v4f wv[9];
        #pragma unroll
        for (int i = 0; i < 9; i++) wv[i] = w4p[lane + (i << 6)];
        v4f wv9 = (v4f)(0.0f);
        bool has9 = lane < rem;
        if (has9) wv9 = w4p[576 + lane];
        float whd = 0.0f, wtl = 0.0f;
        if (lane < h)  whd = lw[base + lane];
        if (lane < tl) wtl = lw[base + KL - tl + lane];

        float* jb = U.p.jbuf[wave];
        for (int id = lane; id < 147; id += 64) {
            int ky = (id * 21846) >> 16;
            int g  = id - 3 * ky;
            int j  = 52 * ky + 49 + g;
            jb[(j & 3) * 640 + (j >> 2)] = 0.0f;
        }
        if (lane < 4) { int j = 2548 + lane; jb[(j & 3) * 640 + (j >> 2)] = 0.0f; }

        float wsum = whd + wtl;
        #pragma unroll
        for (int i = 0; i < 9; i++) wsum += wv[i][0] + wv[i][1] + wv[i][2] + wv[i][3];
        wsum += wv9[0] + wv9[1] + wv9[2] + wv9[3];
        #pragma unroll
        for (int off = 1; off < 64; off <<= 1) wsum += __shfl_xor(wsum, off);
        const float scale = MSCALE / wsum;

        __syncthreads();

        if (lane < h) {
            int k = lane;
            jb[(k & 3) * 640 + (k >> 2)] = whd * lriS[(k & 3) * 601 + (k >> 2)];
        }
        if (lane < tl) {
            int k = KL - tl + lane;
            int ky = (int)(((unsigned)k * 42800u) >> 21);
            int j = k + 3 * ky;
            jb[(j & 3) * 640 + (j >> 2)] = wtl * lriS[(k & 3) * 601 + (k >> 2)];
        }
        #pragma unroll
        for (int i = 0; i < 9; i++) {
            int kq = h + ((lane + (i << 6)) << 2);
            #pragma unroll
            for (int e = 0; e < 4; e++) {
                int k = kq + e;
                int ky = (int)(((unsigned)k * 42800u) >> 21);
                int j = k + 3 * ky;
                jb[(j & 3) * 640 + (j >> 2)] = wv[i][e] * lriS[(k & 3) * 601 + (k >> 2)];
            }
        }
        if (has9) {
            int kq = h + ((576 + lane) << 2);
            #pragma unroll
            for (int e = 0; e < 4; e++) {
                int k = kq + e;
                int ky = (int)(((unsigned)k * 42800u) >> 21);
                int j = k + 3 * ky;
                jb[(j & 3) * 640 + (j >> 2)] = wv9[e] * lriS[(k & 3) * 601 + (k >> 2)];
            }
        }

        v8h* orow = (v8h*)(m16 + (size_t)unit * KJ);
        #pragma unroll
        for (int g = 0; g < 5; g++) {
            int q = lane + (g << 6);
            if (q < 319) {
                int j0 = q << 3;
                v8h st;
                #pragma unroll
                for (int e = 0; e < 8; e++) {
                    int j = j0 + e;
                    st[e] = (_Float16)(jb[(j & 3) * 640 + (j >> 2)] * scale);
                }
                orow[q] = st;
            }
        }
    }
}

// weight loads for one unit row (KJ = 2552 halves = 319 v8h groups)
#define LOADW(P, W0, W1, W2, W3, W4) \
    v8h W0 = (P)[lane]; v8h W1 = (P)[lane + 64]; v8h W2 = (P)[lane + 128]; \
    v8h W3 = (P)[lane + 192]; v8h W4 = (v8h)(_Float16)0.0f; \
    if (lane < 63) W4 = (P)[256 + lane];

// window-order dot: element (group i, elem e) has window index idx = 8*lane + 512*i + (woff+e)
// swizzled dword addr = 2*lane + 128*i + (c&3)*676 + (c>>2), c = woff+e  (2-way conflict = free)
__device__ __forceinline__ float dot_row(v8h w0, v8h w1, v8h w2, v8h w3, v8h w4,
                                         int lane, int woff, const float* win)
{
    float dot = 0.0f;
    const int a0 = lane << 1;
    #pragma unroll
    for (int e = 0; e < 8; e++) {
        const int c = woff + e;
        const int ae = a0 + (c & 3) * 676 + (c >> 2);
        dot = fmaf((float)w0[e], win[ae],       dot);
        dot = fmaf((float)w1[e], win[ae + 128], dot);
        dot = fmaf((float)w2[e], win[ae + 256], dot);
        dot = fmaf((float)w3[e], win[ae + 384], dot);
        dot = fmaf((float)w4[e], win[ae + 512], dot);
    }
    return dot;
}

__device__ __forceinline__ void lat_epi(float dot, int lane, int wave, int du,
    int unit, const float* win, const float* __restrict__ aff,
    const float* __restrict__ lm_in, float* __restrict__ lm_out,
    float* __restrict__ lat_out, float* __restrict__ lat_final)
{
    #pragma unroll
    for (int off = 32; off > 0; off >>= 1) dot += __shfl_down(dot, off);
    if (lane == 0) {
        const int ci = (24 + wave) * 52 + 24 + du;
        const float ls = win[(ci & 3) * 676 + (ci >> 2)];
        float ln = fmaxf(ls + aff[unit] - (2.5f / MSCALE) * dot, 0.0f) * 2.2f;
        ln = tanhf(ln * 1.5f) * (1.0f / 1.5f);
        lm_out[unit] = 0.5f * lm_in[unit] + 0.5f * ln;
        lat_out[unit] = ln;
        if (lat_final) lat_final[unit] = ln;
    }
}

// Fused smooth+lateral iteration (round-3 proven form, 515 us total).
__global__ __launch_bounds__(256) void lat_kernel(
    const _Float16* __restrict__ m16, const float* __restrict__ lat_in,
    const float* __restrict__ sre_g, const float* __restrict__ aff,
    const float* __restrict__ lm_in, float* __restrict__ lm_out,
    float* __restrict__ lat_out, float* __restrict__ lat_final)
{
    __shared__ float raw[3136];
    __shared__ float win[2708];
    const int tid = threadIdx.x;
    const int wave = tid >> 6, lane = tid & 63;
    const int r0 = (blockIdx.x >> 5) << 2, c0 = (blockIdx.x & 31) << 2;

    for (int i = tid; i < 3136; i += 256) {
        int wy = i / 56, wx = i - wy * 56;
        int ar = r0 - 26 + wy; ar = ar < 0 ? -ar : (ar > 127 ? 254 - ar : ar);
        int ac = c0 - 26 + wx; ac = ac < 0 ? -ac : (ac > 127 ? 254 - ac : ac);
        raw[i] = lat_in[ar * 128 + ac];
    }
    if (tid < 4) win[2704 + tid] = 0.0f;

    float sr[25];
    #pragma unroll
    for (int j = 0; j < 25; j++) sr[j] = sre_g[j];

    const int urow = r0 + wave;
    const v8h* p8 = (const v8h*)(m16 + (size_t)(urow * 128 + c0) * KJ);
    LOADW(p8, a0w, a1w, a2w, a3w, a4w)

    __syncthreads();

    for (int i = tid; i < 2704; i += 256) {
        int wr = i / 52, wc = i - wr * 52;
        int arr = r0 - 24 + wr, acl = c0 - 24 + wc;
        float v = 0.0f;
        if (((unsigned)arr < 128u) && ((unsigned)acl < 128u)) {
            const float* rp = raw + wr * 56 + wc;
            float a = 0.0f;
            #pragma unroll
            for (int ay = 0; ay < 5; ay++)
                #pragma unroll
                for (int bx = 0; bx < 5; bx++)
                    a = fmaf(sr[ay * 5 + bx], rp[ay * 56 + bx], a);
            v = a;
        }
        win[(i & 3) * 676 + (i >> 2)] = v;
    }
    __syncthreads();

    const int woff = wave * 52;
    const int ub = urow * 128 + c0;

    const v8h* q1 = (const v8h*)(m16 + (size_t)(ub + 1) * KJ);
    LOADW(q1, b0w, b1w, b2w, b3w, b4w)
    float d0 = dot_row(a0w, a1w, a2w, a3w, a4w, lane, woff + 0, win);
    const v8h* q2 = (const v8h*)(m16 + (size_t)(ub + 2) * KJ);
    LOADW(q2, c0w, c1w, c2w, c3w, c4w)
    lat_epi(d0, lane, wave, 0, ub + 0, win, aff, lm_in, lm_out, lat_out, lat_final);
    float d1 = dot_row(b0w, b1w, b2w, b3w, b4w, lane, woff + 1, win);
    const v8h* q3 = (const v8h*)(m16 + (size_t)(ub + 3) * KJ);
    LOADW(q3, e0w, e1w, e2w, e3w, e4w)
    lat_epi(d1, lane, wave, 1, ub + 1, win, aff, lm_in, lm_out, lat_out, lat_final);
    float d2 = dot_row(c0w, c1w, c2w, c3w, c4w, lane, woff + 2, win);
    lat_epi(d2, lane, wave, 2, ub + 2, win, aff, lm_in, lm_out, lat_out, lat_final);
    float d3 = dot_row(e0w, e1w, e2w, e3w, e4w, lane, woff + 3, win);
    lat_epi(d3, lane, wave, 3, ub + 3, win, aff, lm_in, lm_out, lat_out, lat_final);
}

// Hebbian: same 4x4 tiling, window of lm (zero pad), one atomicAdd per block.
__global__ __launch_bounds__(256) void hebb_kernel(
    const _Float16* __restrict__ m16, const float* __restrict__ lm,
    float* __restrict__ corr)
{
    __shared__ float win[2708];
    __shared__ float wred[4];
    const int tid = threadIdx.x;
    const int wave = tid >> 6, lane = tid & 63;
    const int r0 = (blockIdx.x >> 5) << 2, c0 = (blockIdx.x & 31) << 2;

    for (int i = tid; i < 2704; i += 256) {
        int wr = i / 52, wc = i - wr * 52;
        int ar = r0 - 24 + wr, ac = c0 - 24 + wc;
        float v = 0.0f;
        if (((unsigned)ar < 128u) && ((unsigned)ac < 128u)) v = lm[ar * 128 + ac];
        win[(i & 3) * 676 + (i >> 2)] = v;
    }
    if (tid < 4) win[2704 + tid] = 0.0f;
    __syncthreads();

    const int urow = r0 + wave;
    const int woff = wave * 52;
    float bsum = 0.0f;
    #pragma unroll
    for (int du = 0; du < 4; ++du) {
        const v8h* p = (const v8h*)(m16 + (size_t)(urow * 128 + c0 + du) * KJ);
        LOADW(p, w0, w1, w2, w3, w4)
        float d = dot_row(w0, w1, w2, w3, w4, lane, woff + du, win);
        #pragma unroll
        for (int off = 32; off > 0; off >>= 1) d += __shfl_down(d, off);
        if (lane == 0) {
            const int ci = (24 + wave) * 52 + 24 + du;
            bsum = fmaf(win[(ci & 3) * 676 + (ci >> 2)], d, bsum);
        }
    }
    if (lane == 0) wred[wave] = bsum;
    __syncthreads();
    if (tid == 0)
        atomicAdd(corr, (wred[0] + wred[1] + wred[2] + wred[3]) * (240.1f / MSCALE));
}

extern "C" void kernel_launch(void* const* d_in, const int* in_sizes, int n_in,
                              void* d_out, int out_size, void* d_ws, size_t ws_size,
                              hipStream_t stream) {
    const float* x        = (const float*)d_in[0];
    const float* rfs      = (const float*)d_in[1];
    const float* lw       = (const float*)d_in[2];
    const float* ada      = (const float*)d_in[3];
    const float* last_lat = (const float*)d_in[4];
    const float* lm0      = (const float*)d_in[5];
    float* out = (float*)d_out;
    float* ws  = (float*)d_ws;
    _Float16* m16 = (_Float16*)(ws + WS_M16);

    init_consts<<<1, 256, 0, stream>>>(ws);
    front_kernel<<<8192, 256, 0, stream>>>(x, rfs, ada, ws + WS_AENVD,
                                           out, out + OUT_XT, ws + WS_AFF,
                                           out + OUT_CORR,
                                           lw, ws + WS_LRID, m16);

    float* bufA = ws + WS_LATA;
    float* bufB = ws + WS_LATB;
    for (int it = 0; it < 10; ++it) {
        const float* lat_in = (it == 0) ? last_lat : ((it & 1) ? bufA : bufB);
        float* lat_out = (it & 1) ? bufB : bufA;
        const float* lmsrc = (it == 0) ? lm0 : (ws + WS_LM);
        lat_kernel<<<1024, 256, 0, stream>>>(m16, lat_in, ws + WS_SRE, ws + WS_AFF,
                                             lmsrc, ws + WS_LM, lat_out,
                                             (it == 9) ? (out + OUT_LAT) : nullptr);
    }
    hebb_kernel<<<1024, 256, 0, stream>>>(m16, ws + WS_LM, out + OUT_CORR);
}